// Round 11
// baseline (2141.561 us; speedup 1.0000x reference)
//
#include <hip/hip_runtime.h>

#define D 129
#define N1 8193
#define NN 8192
#define INV_N (1.0f/8192.0f)
#define WSTR 8448        // fp32 row stride for PZ / W
#define KP 160           // padded K (129 -> 160, cols 129..159 zero)
#define TROWS 8448       // rows in ZT/YT (multiple of 256)
#define PSTR 8320        // part row stride (fp32)

typedef __attribute__((ext_vector_type(8))) short bf16x8;
typedef __attribute__((ext_vector_type(4))) float f32x4;
typedef __attribute__((ext_vector_type(4))) unsigned u32x4;
typedef __attribute__((ext_vector_type(2))) unsigned u32x2;

__device__ __forceinline__ short f2bf(float x){
  unsigned u = __float_as_uint(x);
  unsigned r = (u + 0x7fffu + ((u>>16)&1u)) >> 16;
  return (short)r;
}

__device__ __forceinline__ unsigned cvtpk(float a, float b){
  unsigned r; asm("v_cvt_pk_bf16_f32 %0, %1, %2" : "=v"(r) : "v"(a), "v"(b)); return r;
}

__device__ __forceinline__ float bf2f(unsigned short v){
  return __uint_as_float(((unsigned)v)<<16);
}

#define GLOAD_LDS16(gp, lp) __builtin_amdgcn_global_load_lds( \
    (const __attribute__((address_space(1))) void*)(gp),      \
    (__attribute__((address_space(3))) void*)(lp), 16, 0, 0)

// E-row i-permutation: storage position pos -> true i (PV contracts positionally,
// so k_qke stores and k_v's V columns just need the same mapping)
__device__ __forceinline__ int tau(int pos){
  return (pos & 96) + ((pos & 4) << 2) + ((pos & 24) >> 1) + (pos & 3);
}

// ---- transpose fp32 [129][N1] -> bf16 swizzled [t][160]; col 128 = row128, 129..159 = 0
__global__ void k_tr(const float* __restrict__ src, short* __restrict__ dst, int tmax){
  __shared__ float tile[129][65];
  int t0 = blockIdx.x*64, tid = threadIdx.x;
  for(int idx=tid; idx<129*64; idx+=256){
    int d = idx>>6, c = idx&63;
    tile[d][c] = (t0+c < tmax)? src[(size_t)d*N1 + t0+c] : 0.f;
  }
  __syncthreads();
  int q = tid&3, tl = tid>>2;
  int t = t0 + tl;
  short* row = dst + (size_t)t*KP;
  int s7 = t&7;
  #pragma unroll
  for(int g5=0; g5<5; g5++){
    int gi = q*5 + g5;
    bf16x8 v;
    if(gi < 16){
      #pragma unroll
      for(int u=0;u<8;u++) v[u] = f2bf(tile[gi*8+u][tl]);
      *(bf16x8*)(row + ((gi^s7)<<3)) = v;
    } else if(gi == 16){
      v[0] = f2bf(tile[128][tl]);
      #pragma unroll
      for(int u=1;u<8;u++) v[u] = 0;
      *(bf16x8*)(row + (16<<3)) = v;
    } else {
      #pragma unroll
      for(int u=0;u<8;u++) v[u] = 0;
      *(bf16x8*)(row + (gi<<3)) = v;
    }
  }
}

// ---- Y = Q@Z, PZ = P@Z (fp32, K=129), k-split x3 (43 each) + atomicAdd partials
__global__ __launch_bounds__(256) void k_small(
    const float* __restrict__ Z, const float* __restrict__ P,
    const float* __restrict__ Q, float* __restrict__ Yf,
    float* __restrict__ PZ){
  __shared__ float qs[16][44], ps[16][44];
  const int r0 = blockIdx.y*16;
  const int k0 = blockIdx.z*43;
  for(int i=threadIdx.x;i<16*43;i+=256){
    int rr=i/43, cc=i-rr*43;
    float qv=0.f, pv=0.f;
    if(r0+rr<D){ qv=Q[(r0+rr)*D + k0+cc]; pv=P[(r0+rr)*D + k0+cc]; }
    qs[rr][cc]=qv; ps[rr][cc]=pv;
  }
  __syncthreads();
  int t = blockIdx.x*256+threadIdx.x;
  if(t>=N1) return;
  const float* zp = Z + (size_t)k0*N1 + t;
  float ay[16], ap[16];
  #pragma unroll
  for(int rr=0;rr<16;rr++){ ay[rr]=0.f; ap[rr]=0.f; }
  for(int kk=0;kk<40;kk+=4){
    float z0 = zp[(size_t)(kk+0)*N1];
    float z1 = zp[(size_t)(kk+1)*N1];
    float z2 = zp[(size_t)(kk+2)*N1];
    float z3 = zp[(size_t)(kk+3)*N1];
    #pragma unroll
    for(int rr=0;rr<16;rr++){
      float a = ay[rr];
      a = fmaf(qs[rr][kk+0], z0, a);
      a = fmaf(qs[rr][kk+1], z1, a);
      a = fmaf(qs[rr][kk+2], z2, a);
      a = fmaf(qs[rr][kk+3], z3, a);
      ay[rr] = a;
      float b = ap[rr];
      b = fmaf(ps[rr][kk+0], z0, b);
      b = fmaf(ps[rr][kk+1], z1, b);
      b = fmaf(ps[rr][kk+2], z2, b);
      b = fmaf(ps[rr][kk+3], z3, b);
      ap[rr] = b;
    }
  }
  {
    float z0 = zp[(size_t)40*N1];
    float z1 = zp[(size_t)41*N1];
    float z2 = zp[(size_t)42*N1];
    #pragma unroll
    for(int rr=0;rr<16;rr++){
      float a = ay[rr];
      a = fmaf(qs[rr][40], z0, a);
      a = fmaf(qs[rr][41], z1, a);
      a = fmaf(qs[rr][42], z2, a);
      ay[rr] = a;
      float b = ap[rr];
      b = fmaf(ps[rr][40], z0, b);
      b = fmaf(ps[rr][41], z1, b);
      b = fmaf(ps[rr][42], z2, b);
      ap[rr] = b;
    }
  }
  #pragma unroll
  for(int rr=0;rr<16;rr++){
    int r=r0+rr;
    if(r<D){
      atomicAdd(&Yf[(size_t)r*N1+t], ay[rr]);
      atomicAdd(&PZ[(size_t)r*WSTR+t], ap[rr]);
    }
  }
}

// ---- W[d,j] = PZ[d,j] + 0.9*W[d,j+1] (256-tap truncation at 16-chunk heads)
__global__ void k_scan(const float* __restrict__ PZ, float* __restrict__ W){
  __shared__ float s[2376];
  int d = blockIdx.y;
  int base = blockIdx.x*2048;
  for(int i=threadIdx.x;i<2304;i+=128){
    int j = base+i;
    s[i + (i>>5)] = (j<NN)? PZ[(size_t)d*WSTR + j] : 0.f;
  }
  __syncthreads();
  int t = threadIdx.x;
  int jh = t*16+15;
  float acc = 0.f, f = 1.f;
  for(int k=0;k<256;k++){ int a = jh+k; acc = fmaf(f, s[a+(a>>5)], acc); f *= 0.9f; }
  float wv[16];
  wv[15] = acc;
  #pragma unroll
  for(int r=14;r>=0;r--){ int a = t*16+r; wv[r] = fmaf(0.9f, wv[r+1], s[a+(a>>5)]); }
  float* out = W + (size_t)d*WSTR + base + t*16;
  #pragma unroll
  for(int r=0;r<16;r+=4) *(f32x4*)(out+r) = (f32x4){wv[r],wv[r+1],wv[r+2],wv[r+3]};
}

// ---- S[i] = sum over 33 jtb partials
__global__ void k_ssum(const float* __restrict__ S_part, float* __restrict__ S,
                       int i_base, int count){
  int idx = blockIdx.x*256+threadIdx.x;
  if(idx>=count) return;
  int i = i_base + idx;
  float s=0.f;
  #pragma unroll 3
  for(int jtb=0;jtb<33;jtb++) s += S_part[(size_t)jtb*WSTR + i];
  S[i]=s;
}

// ---- V tiles: Vt[it][144 d][128 pos] bf16 (pos -> true i via tau), XOR-swizzled rows
__global__ void k_v(const float* __restrict__ W, const float* __restrict__ S,
                    short* __restrict__ Vt, int tile0){
  int idx = blockIdx.x*256+threadIdx.x;
  int l = idx/18432, rem = idx - l*18432;
  int d = rem>>7, ci = rem&127;
  int it = tile0 + l;
  int i = it*128 + tau(ci);
  float v = (d<=128)? W[(size_t)d*WSTR + i]/S[i] : 0.f;
  int gs = (ci>>3) ^ (d&7);
  Vt[(size_t)it*18432 + (d<<7) + gs*8 + (ci&7)] = f2bf(v);
}

// ---- pass0: X-tile [128 i][256 j] via mfma(Z,Y); E stored bf16 16B/lane;
//      S via latency-free LDS partial grid (no shfl chains, no atomics)
__global__ __launch_bounds__(512,4) void k_qke(
    const short* __restrict__ ZT, const short* __restrict__ YT,
    short* __restrict__ Ebuf, float* __restrict__ S_part, int tile0, int ITC, int nwg){
  __shared__ short zt[128*KP];      // 40960 B
  __shared__ short sp[32*132];      // 8448 B: bf16 pair-partials [wl][i]
  const int tid=threadIdx.x, w=tid>>6, lane=tid&63, g=lane>>4, lm=lane&15;
  // bijective XCD swizzle: consecutive wg (same jtb, consecutive itl) share an XCD
  int bid = blockIdx.x;
  int qq = nwg>>3, rr8 = nwg&7, xcd = bid&7, ix = bid>>3;
  int wg = (xcd<rr8 ? xcd*(qq+1) : rr8*(qq+1)+(xcd-rr8)*qq) + ix;
  const int jtb = wg/ITC, itl = wg - jtb*ITC;
  const int it = tile0 + itl;
  const int sx = lm&7;

  // stage Z tile (contiguous 40960B)
  const short* ztg = ZT + (size_t)it*(128*KP);
  #pragma unroll
  for(int q=0;q<5;q++){
    int off = (q*512 + tid)*8;
    GLOAD_LDS16(ztg + off, zt + off);
  }

  // B-frags: Y rows = X columns j (col = lm, k consecutive)
  bf16x8 b[2][5];
  #pragma unroll
  for(int p=0;p<2;p++){
    int jr = jtb*256 + w*32 + p*16 + lm;
    const short* rp = YT + (size_t)jr*KP;
    #pragma unroll
    for(int kk=0;kk<4;kk++) b[p][kk] = *(const bf16x8*)(rp + (((kk*4+g)^sx)<<3));
    b[p][4] = *(const bf16x8*)(rp + ((16+g)<<3));
  }
  const int jl0 = w*32 + lm, jl1 = jl0 + 16;
  const bool jv0 = (jtb*256 + jl0) < N1;
  const bool jv1 = (jtb*256 + jl1) < N1;
  short* ep0 = Ebuf + ((size_t)(jtb*2 + (jl0>>7))*ITC + itl)*16384 + (jl0&127)*128;
  short* ep1 = Ebuf + ((size_t)(jtb*2 + (jl1>>7))*ITC + itl)*16384 + (jl1&127)*128;
  const int er0 = jl0&7, er1 = jl1&7;
  const int wl = w*4 + (lm>>2);
  __syncthreads();

  #pragma unroll
  for(int p2=0;p2<4;p2++){
    const int ib0 = 2*p2, ib1 = ib0+1;
    f32x4 aA0={0.f,0.f,0.f,0.f}, aA1={0.f,0.f,0.f,0.f};
    f32x4 aB0={0.f,0.f,0.f,0.f}, aB1={0.f,0.f,0.f,0.f};
    const short* zpA = zt + (ib0*16+lm)*KP;
    const short* zpB = zt + (ib1*16+lm)*KP;
    #pragma unroll
    for(int kk=0;kk<4;kk++){
      bf16x8 fa = *(const bf16x8*)(zpA + (((kk*4+g)^sx)<<3));
      bf16x8 fb = *(const bf16x8*)(zpB + (((kk*4+g)^sx)<<3));
      aA0 = __builtin_amdgcn_mfma_f32_16x16x32_bf16(fa, b[0][kk], aA0, 0,0,0);
      aA1 = __builtin_amdgcn_mfma_f32_16x16x32_bf16(fa, b[1][kk], aA1, 0,0,0);
      aB0 = __builtin_amdgcn_mfma_f32_16x16x32_bf16(fb, b[0][kk], aB0, 0,0,0);
      aB1 = __builtin_amdgcn_mfma_f32_16x16x32_bf16(fb, b[1][kk], aB1, 0,0,0);
    }
    {
      bf16x8 fa = *(const bf16x8*)(zpA + ((16+g)<<3));
      bf16x8 fb = *(const bf16x8*)(zpB + ((16+g)<<3));
      aA0 = __builtin_amdgcn_mfma_f32_16x16x32_bf16(fa, b[0][4], aA0, 0,0,0);
      aA1 = __builtin_amdgcn_mfma_f32_16x16x32_bf16(fa, b[1][4], aA1, 0,0,0);
      aB0 = __builtin_amdgcn_mfma_f32_16x16x32_bf16(fb, b[0][4], aB0, 0,0,0);
      aB1 = __builtin_amdgcn_mfma_f32_16x16x32_bf16(fb, b[1][4], aB1, 0,0,0);
    }
    float eA0[4], eA1[4], eB0[4], eB1[4];
    #pragma unroll
    for(int r=0;r<4;r++){
      eA0[r] = jv0 ? __expf(aA0[r]) : 0.f;
      eA1[r] = jv1 ? __expf(aA1[r]) : 0.f;
      eB0[r] = jv0 ? __expf(aB0[r]) : 0.f;
      eB1[r] = jv1 ? __expf(aB1[r]) : 0.f;
    }
    // coalesced 16B stores: pos = p2*32 + g*8 + (ib&1)*4 + r
    const int c0 = p2*4 + g;
    *(u32x4*)(ep0 + ((c0^er0)<<3)) =
      (u32x4){cvtpk(eA0[0],eA0[1]), cvtpk(eA0[2],eA0[3]), cvtpk(eB0[0],eB0[1]), cvtpk(eB0[2],eB0[3])};
    *(u32x4*)(ep1 + ((c0^er1)<<3)) =
      (u32x4){cvtpk(eA1[0],eA1[1]), cvtpk(eA1[2],eA1[3]), cvtpk(eB1[0],eB1[1]), cvtpk(eB1[2],eB1[3])};
    // S partials: 2-hop lm-fold then one b64 LDS write per (p2, half) — no chains/atomics
    float vA[4], vB[4];
    #pragma unroll
    for(int r=0;r<4;r++){
      float sa = eA0[r] + eA1[r];
      sa += __shfl_xor(sa,1); sa += __shfl_xor(sa,2);
      vA[r]=sa;
      float sb = eB0[r] + eB1[r];
      sb += __shfl_xor(sb,1); sb += __shfl_xor(sb,2);
      vB[r]=sb;
    }
    if((lm&3)==0){
      int i0 = p2*32 + g*4;
      *(u32x2*)(sp + wl*132 + i0)      = (u32x2){cvtpk(vA[0],vA[1]), cvtpk(vA[2],vA[3])};
      *(u32x2*)(sp + wl*132 + i0 + 16) = (u32x2){cvtpk(vB[0],vB[1]), cvtpk(vB[2],vB[3])};
    }
  }
  __syncthreads();
  // final reduce: thread (i=tid>>2, q=tid&3) sums 8 wl slots, 2-shfl fold over q
  {
    int i = tid>>2, q = tid&3;
    float s=0.f;
    #pragma unroll
    for(int k=0;k<8;k++) s += bf2f((unsigned short)sp[(q*8+k)*132 + i]);
    s += __shfl_xor(s,1); s += __shfl_xor(s,2);
    if(q==0) S_part[(size_t)jtb*WSTR + it*128 + i] = s;
  }
}

// ---- pass1: part[ks][144 d][128 j] = V @ E over nT i-tiles. LDS-staged, double-buffered.
__global__ __launch_bounds__(512) void k_pv(
    const short* __restrict__ Ebuf, const short* __restrict__ Vt,
    float* __restrict__ part, int ITC, int tile0, int ks_base, int nT){
  __shared__ short lds[2][34816];     // [buf]: E tile 16384 shorts + V tile 18432 shorts
  const int tid=threadIdx.x, w=tid>>6, lane=tid&63, g=lane>>4, lm=lane&15;
  const int jt = blockIdx.x;
  const int ks = ks_base + blockIdx.y;
  const int t0l = blockIdx.y*nT;      // local tile index base within this chunk
  const int sx = lm&7;

  f32x4 acc[9];
  #pragma unroll
  for(int m=0;m<9;m++) acc[m] = (f32x4){0.f,0.f,0.f,0.f};

  auto stage = [&](int buf, int tl){
    const short* eg = Ebuf + ((size_t)jt*ITC + tl)*16384;
    short* eb = &lds[buf][0];
    #pragma unroll
    for(int q=0;q<4;q++){
      int off = (q*512 + tid)*8;
      GLOAD_LDS16(eg + off, eb + off);
    }
    const short* vg = Vt + (size_t)(tile0 + tl)*18432;
    short* vb = &lds[buf][16384];
    #pragma unroll
    for(int q=0;q<5;q++){
      int off = (q*512 + tid)*8;
      if(q<4 || tid<256) GLOAD_LDS16(vg + off, vb + off);
    }
  };

  stage(0, t0l);
  __syncthreads();

  for(int t=0; t<nT; ++t){
    if(t+1<nT) stage((t+1)&1, t0l+t+1);
    const short* eb = &lds[t&1][0];
    const short* vb = &lds[t&1][16384];
    const short* ep = eb + (w*16+lm)*128;
    #pragma unroll
    for(int kk=0;kk<4;kk++){
      int go = ((kk*4+g)^sx)<<3;
      bf16x8 b = *(const bf16x8*)(ep + go);
      #pragma unroll
      for(int m=0;m<9;m++){
        bf16x8 av = *(const bf16x8*)(vb + ((m*16+lm)<<7) + go);
        acc[m] = __builtin_amdgcn_mfma_f32_16x16x32_bf16(av, b, acc[m], 0,0,0);
      }
    }
    __syncthreads();
  }

  float* pb = part + (size_t)ks*144*PSTR;
  const int j = jt*128 + w*16 + lm;
  #pragma unroll
  for(int m=0;m<9;m++){
    #pragma unroll
    for(int r=0;r<4;r++)
      pb[(size_t)(m*16+g*4+r)*PSTR + j] = acc[m][r];
  }
}

// ---- out = Zc + INV_N * sum_ks part[ks]
__global__ void k_out(const float* __restrict__ Zc, const float* __restrict__ part,
                      float* __restrict__ out, int st){
  int idx = blockIdx.x*256+threadIdx.x;
  if(idx >= 129*2049) return;
  int d = idx/2049, jq = idx - d*2049;
  int j0 = jq*4;
  float s0=0.f,s1=0.f,s2=0.f,s3=0.f;
  for(int ks=0;ks<st;ks++){
    f32x4 v = *(const f32x4*)(part + (size_t)ks*144*PSTR + (size_t)d*PSTR + j0);
    s0+=v[0]; s1+=v[1]; s2+=v[2]; s3+=v[3];
  }
  const float* zr = Zc + (size_t)d*N1;
  float* orow = out + (size_t)d*N1;
  float sv[4] = {s0,s1,s2,s3};
  #pragma unroll
  for(int u=0;u<4;u++){
    int j = j0+u;
    if(j < N1) orow[j] = zr[j] + INV_N*sv[u];
  }
}

extern "C" void kernel_launch(void* const* d_in, const int* in_sizes, int n_in,
                              void* d_out, int out_size, void* d_ws, size_t ws_size,
                              hipStream_t stream){
  (void)in_sizes; (void)n_in; (void)out_size;
  const float* Zin=(const float*)d_in[0];
  const float* Pm =(const float*)d_in[1];
  const float* Qm =(const float*)d_in[2];
  float* out=(float*)d_out;

  // config ladder: c chunks of i-tiles; k_pv grid y = ksPC stripes per chunk; st = c*ksPC
  const size_t fixed = 3*(size_t)D*N1*4 + 2*(size_t)D*WSTR*4 + (size_t)WSTR*4
                     + (size_t)33*WSTR*4
                     + 2*(size_t)TROWS*KP*2 + (size_t)64*18432*2 + 16*4096;
  int c=8, ksPC=1;
  {
    const int cs[5] = {1,1,2,4,8};
    const int kp[5] = {8,4,2,1,1};
    for(int k=0;k<5;k++){
      int stc = cs[k]*kp[k];
      size_t need = fixed + (size_t)stc*144*PSTR*4 + (size_t)66*(64/cs[k])*16384*2;
      if(need <= ws_size){ c=cs[k]; ksPC=kp[k]; break; }
    }
  }
  const int ITC = 64/c, nT = ITC/ksPC, st = c*ksPC;

  char* base=(char*)d_ws;
  size_t off=0;
  auto alloc=[&](size_t b)->void*{ void* p=base+off; off=(off+b+255)&~(size_t)255; return p; };
  float* Z0  =(float*)alloc((size_t)D*N1*4);
  float* Z1  =(float*)alloc((size_t)D*N1*4);
  float* Yf  =(float*)alloc((size_t)D*N1*4);
  float* PZ  =(float*)alloc((size_t)D*WSTR*4);
  float* Wf  =(float*)alloc((size_t)D*WSTR*4);
  float* S   =(float*)alloc((size_t)WSTR*4);
  float* Sp  =(float*)alloc((size_t)33*WSTR*4);
  short* ZT  =(short*)alloc((size_t)TROWS*KP*2);
  short* YT  =(short*)alloc((size_t)TROWS*KP*2);
  short* Vt  =(short*)alloc((size_t)64*18432*2);
  float* part=(float*)alloc((size_t)st*144*PSTR*4);
  short* Ebuf=(short*)alloc((size_t)66*ITC*16384*2);

  const float* Zc=Zin;
  for(int l=0;l<4;l++){
    float* Zn = (l==3)? out : ((l&1)? Z1:Z0);
    hipMemsetAsync(Yf,0,(size_t)D*N1*4,stream);
    hipMemsetAsync(PZ,0,(size_t)D*WSTR*4,stream);
    k_small<<<dim3(33,9,3),dim3(256),0,stream>>>(Zc,Pm,Qm,Yf,PZ);
    k_tr<<<dim3(132),dim3(256),0,stream>>>(Zc,ZT,N1);
    k_tr<<<dim3(132),dim3(256),0,stream>>>(Yf,YT,N1);
    k_scan<<<dim3(4,D),dim3(128),0,stream>>>(PZ,Wf);
    for(int ch=0; ch<c; ch++){
      int tile0 = ch*ITC;
      int nwg = 33*ITC;
      k_qke<<<dim3(nwg),dim3(512),0,stream>>>(ZT,YT,Ebuf,Sp,tile0,ITC,nwg);
      k_ssum<<<dim3((ITC*128+255)/256),dim3(256),0,stream>>>(Sp,S,tile0*128,ITC*128);
      k_v<<<dim3(ITC*72),dim3(256),0,stream>>>(Wf,S,Vt,tile0);
      k_pv<<<dim3(65,ksPC),dim3(512),0,stream>>>(Ebuf,Vt,part,ITC,tile0,ch*ksPC,nT);
    }
    k_out<<<dim3(1033),dim3(256),0,stream>>>(Zc,part,Zn,st);
    Zc=Zn;
  }
}

// Round 12
// 639.680 us; speedup vs baseline: 3.3479x; 3.3479x over previous
//
#include <hip/hip_runtime.h>

#define D 129
#define N1 8193
#define NN 8192
#define INV_N (1.0f/8192.0f)
#define WSTR 8448        // fp32 row stride for PZ / W
#define KP 160           // padded K (129 -> 160, cols 129..159 zero)
#define TROWS 8448       // rows in ZT/YT (multiple of 256)
#define PSTR 8320        // part row stride (fp32)

typedef __attribute__((ext_vector_type(8))) short bf16x8;
typedef __attribute__((ext_vector_type(4))) float f32x4;
typedef __attribute__((ext_vector_type(4))) unsigned u32x4;
typedef __attribute__((ext_vector_type(2))) unsigned u32x2;

__device__ __forceinline__ short f2bf(float x){
  unsigned u = __float_as_uint(x);
  unsigned r = (u + 0x7fffu + ((u>>16)&1u)) >> 16;
  return (short)r;
}

__device__ __forceinline__ unsigned cvtpk(float a, float b){
  unsigned r; asm("v_cvt_pk_bf16_f32 %0, %1, %2" : "=v"(r) : "v"(a), "v"(b)); return r;
}

__device__ __forceinline__ float bf2f(unsigned short v){
  return __uint_as_float(((unsigned)v)<<16);
}

#define GLOAD_LDS16(gp, lp) __builtin_amdgcn_global_load_lds( \
    (const __attribute__((address_space(1))) void*)(gp),      \
    (__attribute__((address_space(3))) void*)(lp), 16, 0, 0)

// E-row i-permutation: storage position pos -> true i (PV contracts positionally,
// so k_qke stores and k_v's V columns just need the same mapping)
__device__ __forceinline__ int tau(int pos){
  return (pos & 96) + ((pos & 4) << 2) + ((pos & 24) >> 1) + (pos & 3);
}

// ---- transpose fp32 [129][N1] -> bf16 swizzled [t][160]; col 128 = row128, 129..159 = 0
__global__ void k_tr(const float* __restrict__ src, short* __restrict__ dst, int tmax){
  __shared__ float tile[129][65];
  int t0 = blockIdx.x*64, tid = threadIdx.x;
  for(int idx=tid; idx<129*64; idx+=256){
    int d = idx>>6, c = idx&63;
    tile[d][c] = (t0+c < tmax)? src[(size_t)d*N1 + t0+c] : 0.f;
  }
  __syncthreads();
  int q = tid&3, tl = tid>>2;
  int t = t0 + tl;
  short* row = dst + (size_t)t*KP;
  int s7 = t&7;
  #pragma unroll
  for(int g5=0; g5<5; g5++){
    int gi = q*5 + g5;
    bf16x8 v;
    if(gi < 16){
      #pragma unroll
      for(int u=0;u<8;u++) v[u] = f2bf(tile[gi*8+u][tl]);
      *(bf16x8*)(row + ((gi^s7)<<3)) = v;
    } else if(gi == 16){
      v[0] = f2bf(tile[128][tl]);
      #pragma unroll
      for(int u=1;u<8;u++) v[u] = 0;
      *(bf16x8*)(row + (16<<3)) = v;
    } else {
      #pragma unroll
      for(int u=0;u<8;u++) v[u] = 0;
      *(bf16x8*)(row + (gi<<3)) = v;
    }
  }
}

// ---- Y=Q@Z (written straight to YT bf16 swizzled), PZ=P@Z (fp32).
// grid (33,17) x 512 thr: 8 rows/block, in-block k-split x2, LDS reduce.
__global__ __launch_bounds__(512) void k_small(
    const float* __restrict__ Z, const float* __restrict__ P,
    const float* __restrict__ Q, short* __restrict__ YT,
    float* __restrict__ PZ){
  __shared__ float qs[8][132], ps[8][132];
  __shared__ float red[16*256];
  const int tid = threadIdx.x, tx = tid&255, kg = tid>>8;
  const int r0 = blockIdx.y*8;
  for(int i=tid;i<8*129;i+=512){
    int rr=i/129, cc=i-rr*129;
    float qv=0.f, pv=0.f;
    if(r0+rr<D){ qv=Q[(r0+rr)*D+cc]; pv=P[(r0+rr)*D+cc]; }
    qs[rr][cc]=qv; ps[rr][cc]=pv;
  }
  __syncthreads();
  const int t = blockIdx.x*256 + tx;
  const bool valid = (t < N1);
  const int tc = valid ? t : (N1-1);
  const float* zp = Z + tc;
  float ay[8], ap[8];
  #pragma unroll
  for(int rr=0;rr<8;rr++){ ay[rr]=0.f; ap[rr]=0.f; }
  const int kbeg = kg ? 65 : 0, kend = kg ? 129 : 65;
  for(int k=kbeg;k<kend;k++){
    float z = zp[(size_t)k*N1];
    #pragma unroll
    for(int rr=0;rr<8;rr++){
      ay[rr] = fmaf(qs[rr][k], z, ay[rr]);
      ap[rr] = fmaf(ps[rr][k], z, ap[rr]);
    }
  }
  if(kg==1){
    #pragma unroll
    for(int rr=0;rr<8;rr++){
      red[rr*256+tx]     = ay[rr];
      red[(8+rr)*256+tx] = ap[rr];
    }
  }
  __syncthreads();
  if(kg==0){
    #pragma unroll
    for(int rr=0;rr<8;rr++){
      ay[rr] += red[rr*256+tx];
      ap[rr] += red[(8+rr)*256+tx];
    }
    // YT row t: this block's 8 m-values form exactly one 16B chunk gc=r0>>3
    short* row = YT + (size_t)t*KP;
    const int s7 = t&7;
    const int gc = r0>>3;
    bf16x8 v;
    #pragma unroll
    for(int u=0;u<8;u++) v[u] = f2bf(valid ? ay[u] : 0.f);
    if(gc < 16){
      *(bf16x8*)(row + ((gc^s7)<<3)) = v;
    } else {
      *(bf16x8*)(row + (16<<3)) = v;          // m=128..135 (only m=128 nonzero)
      bf16x8 zv;
      #pragma unroll
      for(int u=0;u<8;u++) zv[u]=0;
      *(bf16x8*)(row + (17<<3)) = zv;
      *(bf16x8*)(row + (18<<3)) = zv;
      *(bf16x8*)(row + (19<<3)) = zv;
    }
    // PZ fp32 rows r0..r0+7 (coalesced over t)
    #pragma unroll
    for(int rr=0;rr<8;rr++){
      int r=r0+rr;
      if(r<D) PZ[(size_t)r*WSTR + t] = valid ? ap[rr] : 0.f;
    }
  }
}

// ---- W[d,j] = PZ[d,j] + 0.9*W[d,j+1] (256-tap truncation at 16-chunk heads)
__global__ void k_scan(const float* __restrict__ PZ, float* __restrict__ W){
  __shared__ float s[2376];
  int d = blockIdx.y;
  int base = blockIdx.x*2048;
  for(int i=threadIdx.x;i<2304;i+=128){
    int j = base+i;
    s[i + (i>>5)] = (j<NN)? PZ[(size_t)d*WSTR + j] : 0.f;
  }
  __syncthreads();
  int t = threadIdx.x;
  int jh = t*16+15;
  float acc = 0.f, f = 1.f;
  for(int k=0;k<256;k++){ int a = jh+k; acc = fmaf(f, s[a+(a>>5)], acc); f *= 0.9f; }
  float wv[16];
  wv[15] = acc;
  #pragma unroll
  for(int r=14;r>=0;r--){ int a = t*16+r; wv[r] = fmaf(0.9f, wv[r+1], s[a+(a>>5)]); }
  float* out = W + (size_t)d*WSTR + base + t*16;
  #pragma unroll
  for(int r=0;r<16;r+=4) *(f32x4*)(out+r) = (f32x4){wv[r],wv[r+1],wv[r+2],wv[r+3]};
}

// ---- S[i] = sum over 33 jtb partials
__global__ void k_ssum(const float* __restrict__ S_part, float* __restrict__ S,
                       int i_base, int count){
  int idx = blockIdx.x*256+threadIdx.x;
  if(idx>=count) return;
  int i = i_base + idx;
  float s=0.f;
  #pragma unroll 3
  for(int jtb=0;jtb<33;jtb++) s += S_part[(size_t)jtb*WSTR + i];
  S[i]=s;
}

// ---- V tiles: Vt[it][144 d][128 pos] bf16 (pos -> true i via tau), XOR-swizzled rows
__global__ void k_v(const float* __restrict__ W, const float* __restrict__ S,
                    short* __restrict__ Vt, int tile0){
  int idx = blockIdx.x*256+threadIdx.x;
  int l = idx/18432, rem = idx - l*18432;
  int d = rem>>7, ci = rem&127;
  int it = tile0 + l;
  int i = it*128 + tau(ci);
  float v = (d<=128)? W[(size_t)d*WSTR + i]/S[i] : 0.f;
  int gs = (ci>>3) ^ (d&7);
  Vt[(size_t)it*18432 + (d<<7) + gs*8 + (ci&7)] = f2bf(v);
}

// ---- pass0: X-tile [128 i][256 j] via mfma(Z,Y); E stored bf16 16B/lane;
//      S via latency-free LDS partial grid (no shfl chains, no atomics)
__global__ __launch_bounds__(512,4) void k_qke(
    const short* __restrict__ ZT, const short* __restrict__ YT,
    short* __restrict__ Ebuf, float* __restrict__ S_part, int tile0, int ITC, int nwg){
  __shared__ short zt[128*KP];      // 40960 B
  __shared__ short sp[32*132];      // 8448 B: bf16 pair-partials [wl][i]
  const int tid=threadIdx.x, w=tid>>6, lane=tid&63, g=lane>>4, lm=lane&15;
  // bijective XCD swizzle: consecutive wg (same jtb, consecutive itl) share an XCD
  int bid = blockIdx.x;
  int qq = nwg>>3, rr8 = nwg&7, xcd = bid&7, ix = bid>>3;
  int wg = (xcd<rr8 ? xcd*(qq+1) : rr8*(qq+1)+(xcd-rr8)*qq) + ix;
  const int jtb = wg/ITC, itl = wg - jtb*ITC;
  const int it = tile0 + itl;
  const int sx = lm&7;

  // stage Z tile (contiguous 40960B)
  const short* ztg = ZT + (size_t)it*(128*KP);
  #pragma unroll
  for(int q=0;q<5;q++){
    int off = (q*512 + tid)*8;
    GLOAD_LDS16(ztg + off, zt + off);
  }

  // B-frags: Y rows = X columns j (col = lm, k consecutive)
  bf16x8 b[2][5];
  #pragma unroll
  for(int p=0;p<2;p++){
    int jr = jtb*256 + w*32 + p*16 + lm;
    const short* rp = YT + (size_t)jr*KP;
    #pragma unroll
    for(int kk=0;kk<4;kk++) b[p][kk] = *(const bf16x8*)(rp + (((kk*4+g)^sx)<<3));
    b[p][4] = *(const bf16x8*)(rp + ((16+g)<<3));
  }
  const int jl0 = w*32 + lm, jl1 = jl0 + 16;
  const bool jv0 = (jtb*256 + jl0) < N1;
  const bool jv1 = (jtb*256 + jl1) < N1;
  short* ep0 = Ebuf + ((size_t)(jtb*2 + (jl0>>7))*ITC + itl)*16384 + (jl0&127)*128;
  short* ep1 = Ebuf + ((size_t)(jtb*2 + (jl1>>7))*ITC + itl)*16384 + (jl1&127)*128;
  const int er0 = jl0&7, er1 = jl1&7;
  const int wl = w*4 + (lm>>2);
  __syncthreads();

  #pragma unroll
  for(int p2=0;p2<4;p2++){
    const int ib0 = 2*p2, ib1 = ib0+1;
    f32x4 aA0={0.f,0.f,0.f,0.f}, aA1={0.f,0.f,0.f,0.f};
    f32x4 aB0={0.f,0.f,0.f,0.f}, aB1={0.f,0.f,0.f,0.f};
    const short* zpA = zt + (ib0*16+lm)*KP;
    const short* zpB = zt + (ib1*16+lm)*KP;
    #pragma unroll
    for(int kk=0;kk<4;kk++){
      bf16x8 fa = *(const bf16x8*)(zpA + (((kk*4+g)^sx)<<3));
      bf16x8 fb = *(const bf16x8*)(zpB + (((kk*4+g)^sx)<<3));
      aA0 = __builtin_amdgcn_mfma_f32_16x16x32_bf16(fa, b[0][kk], aA0, 0,0,0);
      aA1 = __builtin_amdgcn_mfma_f32_16x16x32_bf16(fa, b[1][kk], aA1, 0,0,0);
      aB0 = __builtin_amdgcn_mfma_f32_16x16x32_bf16(fb, b[0][kk], aB0, 0,0,0);
      aB1 = __builtin_amdgcn_mfma_f32_16x16x32_bf16(fb, b[1][kk], aB1, 0,0,0);
    }
    {
      bf16x8 fa = *(const bf16x8*)(zpA + ((16+g)<<3));
      bf16x8 fb = *(const bf16x8*)(zpB + ((16+g)<<3));
      aA0 = __builtin_amdgcn_mfma_f32_16x16x32_bf16(fa, b[0][4], aA0, 0,0,0);
      aA1 = __builtin_amdgcn_mfma_f32_16x16x32_bf16(fa, b[1][4], aA1, 0,0,0);
      aB0 = __builtin_amdgcn_mfma_f32_16x16x32_bf16(fb, b[0][4], aB0, 0,0,0);
      aB1 = __builtin_amdgcn_mfma_f32_16x16x32_bf16(fb, b[1][4], aB1, 0,0,0);
    }
    float eA0[4], eA1[4], eB0[4], eB1[4];
    #pragma unroll
    for(int r=0;r<4;r++){
      eA0[r] = jv0 ? __expf(aA0[r]) : 0.f;
      eA1[r] = jv1 ? __expf(aA1[r]) : 0.f;
      eB0[r] = jv0 ? __expf(aB0[r]) : 0.f;
      eB1[r] = jv1 ? __expf(aB1[r]) : 0.f;
    }
    // coalesced 16B stores: pos = p2*32 + g*8 + (ib&1)*4 + r
    const int c0 = p2*4 + g;
    *(u32x4*)(ep0 + ((c0^er0)<<3)) =
      (u32x4){cvtpk(eA0[0],eA0[1]), cvtpk(eA0[2],eA0[3]), cvtpk(eB0[0],eB0[1]), cvtpk(eB0[2],eB0[3])};
    *(u32x4*)(ep1 + ((c0^er1)<<3)) =
      (u32x4){cvtpk(eA1[0],eA1[1]), cvtpk(eA1[2],eA1[3]), cvtpk(eB1[0],eB1[1]), cvtpk(eB1[2],eB1[3])};
    // S partials: 2-hop lm-fold then one b64 LDS write per (p2, half) — no chains/atomics
    float vA[4], vB[4];
    #pragma unroll
    for(int r=0;r<4;r++){
      float sa = eA0[r] + eA1[r];
      sa += __shfl_xor(sa,1); sa += __shfl_xor(sa,2);
      vA[r]=sa;
      float sb = eB0[r] + eB1[r];
      sb += __shfl_xor(sb,1); sb += __shfl_xor(sb,2);
      vB[r]=sb;
    }
    if((lm&3)==0){
      int i0 = p2*32 + g*4;
      *(u32x2*)(sp + wl*132 + i0)      = (u32x2){cvtpk(vA[0],vA[1]), cvtpk(vA[2],vA[3])};
      *(u32x2*)(sp + wl*132 + i0 + 16) = (u32x2){cvtpk(vB[0],vB[1]), cvtpk(vB[2],vB[3])};
    }
  }
  __syncthreads();
  // final reduce: thread (i=tid>>2, q=tid&3) sums 8 wl slots, 2-shfl fold over q
  {
    int i = tid>>2, q = tid&3;
    float s=0.f;
    #pragma unroll
    for(int k=0;k<8;k++) s += bf2f((unsigned short)sp[(q*8+k)*132 + i]);
    s += __shfl_xor(s,1); s += __shfl_xor(s,2);
    if(q==0) S_part[(size_t)jtb*WSTR + it*128 + i] = s;
  }
}

// ---- pass1: part[ks][144 d][128 j] = V @ E over nT i-tiles. LDS-staged, double-buffered.
__global__ __launch_bounds__(512) void k_pv(
    const short* __restrict__ Ebuf, const short* __restrict__ Vt,
    float* __restrict__ part, int ITC, int tile0, int ks_base, int nT){
  __shared__ short lds[2][34816];     // [buf]: E tile 16384 shorts + V tile 18432 shorts
  const int tid=threadIdx.x, w=tid>>6, lane=tid&63, g=lane>>4, lm=lane&15;
  const int jt = blockIdx.x;
  const int ks = ks_base + blockIdx.y;
  const int t0l = blockIdx.y*nT;      // local tile index base within this chunk
  const int sx = lm&7;

  f32x4 acc[9];
  #pragma unroll
  for(int m=0;m<9;m++) acc[m] = (f32x4){0.f,0.f,0.f,0.f};

  auto stage = [&](int buf, int tl){
    const short* eg = Ebuf + ((size_t)jt*ITC + tl)*16384;
    short* eb = &lds[buf][0];
    #pragma unroll
    for(int q=0;q<4;q++){
      int off = (q*512 + tid)*8;
      GLOAD_LDS16(eg + off, eb + off);
    }
    const short* vg = Vt + (size_t)(tile0 + tl)*18432;
    short* vb = &lds[buf][16384];
    #pragma unroll
    for(int q=0;q<5;q++){
      int off = (q*512 + tid)*8;
      if(q<4 || tid<256) GLOAD_LDS16(vg + off, vb + off);
    }
  };

  stage(0, t0l);
  __syncthreads();

  for(int t=0; t<nT; ++t){
    if(t+1<nT) stage((t+1)&1, t0l+t+1);
    const short* eb = &lds[t&1][0];
    const short* vb = &lds[t&1][16384];
    const short* ep = eb + (w*16+lm)*128;
    #pragma unroll
    for(int kk=0;kk<4;kk++){
      int go = ((kk*4+g)^sx)<<3;
      bf16x8 b = *(const bf16x8*)(ep + go);
      #pragma unroll
      for(int m=0;m<9;m++){
        bf16x8 av = *(const bf16x8*)(vb + ((m*16+lm)<<7) + go);
        acc[m] = __builtin_amdgcn_mfma_f32_16x16x32_bf16(av, b, acc[m], 0,0,0);
      }
    }
    __syncthreads();
  }

  float* pb = part + (size_t)ks*144*PSTR;
  const int j = jt*128 + w*16 + lm;
  #pragma unroll
  for(int m=0;m<9;m++){
    #pragma unroll
    for(int r=0;r<4;r++)
      pb[(size_t)(m*16+g*4+r)*PSTR + j] = acc[m][r];
  }
}

// ---- out = Zc + INV_N * sum_ks part[ks]
__global__ void k_out(const float* __restrict__ Zc, const float* __restrict__ part,
                      float* __restrict__ out, int st){
  int idx = blockIdx.x*256+threadIdx.x;
  if(idx >= 129*2049) return;
  int d = idx/2049, jq = idx - d*2049;
  int j0 = jq*4;
  float s0=0.f,s1=0.f,s2=0.f,s3=0.f;
  for(int ks=0;ks<st;ks++){
    f32x4 v = *(const f32x4*)(part + (size_t)ks*144*PSTR + (size_t)d*PSTR + j0);
    s0+=v[0]; s1+=v[1]; s2+=v[2]; s3+=v[3];
  }
  const float* zr = Zc + (size_t)d*N1;
  float* orow = out + (size_t)d*N1;
  float sv[4] = {s0,s1,s2,s3};
  #pragma unroll
  for(int u=0;u<4;u++){
    int j = j0+u;
    if(j < N1) orow[j] = zr[j] + INV_N*sv[u];
  }
}

extern "C" void kernel_launch(void* const* d_in, const int* in_sizes, int n_in,
                              void* d_out, int out_size, void* d_ws, size_t ws_size,
                              hipStream_t stream){
  (void)in_sizes; (void)n_in; (void)out_size;
  const float* Zin=(const float*)d_in[0];
  const float* Pm =(const float*)d_in[1];
  const float* Qm =(const float*)d_in[2];
  float* out=(float*)d_out;

  // config ladder: c chunks of i-tiles; k_pv grid y = ksPC stripes per chunk; st = c*ksPC
  const size_t fixed = 2*(size_t)D*N1*4 + 2*(size_t)D*WSTR*4 + (size_t)WSTR*4
                     + (size_t)33*WSTR*4
                     + 2*(size_t)TROWS*KP*2 + (size_t)64*18432*2 + 16*4096;
  int c=8, ksPC=1;
  {
    const int cs[5] = {1,1,2,4,8};
    const int kp[5] = {8,4,2,1,1};
    for(int k=0;k<5;k++){
      int stc = cs[k]*kp[k];
      size_t need = fixed + (size_t)stc*144*PSTR*4 + (size_t)66*(64/cs[k])*16384*2;
      if(need <= ws_size){ c=cs[k]; ksPC=kp[k]; break; }
    }
  }
  const int ITC = 64/c, nT = ITC/ksPC, st = c*ksPC;

  char* base=(char*)d_ws;
  size_t off=0;
  auto alloc=[&](size_t b)->void*{ void* p=base+off; off=(off+b+255)&~(size_t)255; return p; };
  float* Z0  =(float*)alloc((size_t)D*N1*4);
  float* Z1  =(float*)alloc((size_t)D*N1*4);
  float* PZ  =(float*)alloc((size_t)D*WSTR*4);
  float* Wf  =(float*)alloc((size_t)D*WSTR*4);
  float* S   =(float*)alloc((size_t)WSTR*4);
  float* Sp  =(float*)alloc((size_t)33*WSTR*4);
  short* ZT  =(short*)alloc((size_t)TROWS*KP*2);
  short* YT  =(short*)alloc((size_t)TROWS*KP*2);
  short* Vt  =(short*)alloc((size_t)64*18432*2);
  float* part=(float*)alloc((size_t)st*144*PSTR*4);
  short* Ebuf=(short*)alloc((size_t)66*ITC*16384*2);

  const float* Zc=Zin;
  for(int l=0;l<4;l++){
    float* Zn = (l==3)? out : ((l&1)? Z1:Z0);
    k_small<<<dim3(33,17),dim3(512),0,stream>>>(Zc,Pm,Qm,YT,PZ);
    k_tr<<<dim3(132),dim3(256),0,stream>>>(Zc,ZT,N1);
    k_scan<<<dim3(4,D),dim3(128),0,stream>>>(PZ,Wf);
    for(int ch=0; ch<c; ch++){
      int tile0 = ch*ITC;
      int nwg = 33*ITC;
      k_qke<<<dim3(nwg),dim3(512),0,stream>>>(ZT,YT,Ebuf,Sp,tile0,ITC,nwg);
      k_ssum<<<dim3((ITC*128+255)/256),dim3(256),0,stream>>>(Sp,S,tile0*128,ITC*128);
      k_v<<<dim3(ITC*72),dim3(256),0,stream>>>(Wf,S,Vt,tile0);
      k_pv<<<dim3(65,ksPC),dim3(512),0,stream>>>(Ebuf,Vt,part,ITC,tile0,ch*ksPC,nT);
    }
    k_out<<<dim3(1033),dim3(256),0,stream>>>(Zc,part,Zn,st);
    Zc=Zn;
  }
}

// Round 13
// 626.139 us; speedup vs baseline: 3.4203x; 1.0216x over previous
//
#include <hip/hip_runtime.h>

#define D 129
#define N1 8193
#define NN 8192
#define INV_N (1.0f/8192.0f)
#define WSTR 8448        // fp32 row stride for PZ / W
#define KP 160           // padded K (129 -> 160, cols 129..159 zero)
#define TROWS 8448       // rows in ZT/YT (multiple of 256)
#define PSTR 8320        // part row stride (fp32)

typedef __attribute__((ext_vector_type(8))) short bf16x8;
typedef __attribute__((ext_vector_type(4))) float f32x4;
typedef __attribute__((ext_vector_type(4))) unsigned u32x4;
typedef __attribute__((ext_vector_type(2))) unsigned u32x2;

__device__ __forceinline__ short f2bf(float x){
  unsigned u = __float_as_uint(x);
  unsigned r = (u + 0x7fffu + ((u>>16)&1u)) >> 16;
  return (short)r;
}

__device__ __forceinline__ unsigned cvtpk(float a, float b){
  unsigned r; asm("v_cvt_pk_bf16_f32 %0, %1, %2" : "=v"(r) : "v"(a), "v"(b)); return r;
}

__device__ __forceinline__ float bf2f(unsigned short v){
  return __uint_as_float(((unsigned)v)<<16);
}

#define GLOAD_LDS16(gp, lp) __builtin_amdgcn_global_load_lds( \
    (const __attribute__((address_space(1))) void*)(gp),      \
    (__attribute__((address_space(3))) void*)(lp), 16, 0, 0)

// E-row i-permutation: storage position pos -> true i (PV contracts positionally,
// so k_qke stores and k_v's V columns just need the same mapping)
__device__ __forceinline__ int tau(int pos){
  return (pos & 96) + ((pos & 4) << 2) + ((pos & 24) >> 1) + (pos & 3);
}

// ---- transpose fp32 [129][N1] -> bf16 swizzled [t][160]; col 128 = row128, 129..159 = 0
__global__ void k_tr(const float* __restrict__ src, short* __restrict__ dst, int tmax){
  __shared__ float tile[129][65];
  int t0 = blockIdx.x*64, tid = threadIdx.x;
  for(int idx=tid; idx<129*64; idx+=256){
    int d = idx>>6, c = idx&63;
    tile[d][c] = (t0+c < tmax)? src[(size_t)d*N1 + t0+c] : 0.f;
  }
  __syncthreads();
  int q = tid&3, tl = tid>>2;
  int t = t0 + tl;
  short* row = dst + (size_t)t*KP;
  int s7 = t&7;
  #pragma unroll
  for(int g5=0; g5<5; g5++){
    int gi = q*5 + g5;
    bf16x8 v;
    if(gi < 16){
      #pragma unroll
      for(int u=0;u<8;u++) v[u] = f2bf(tile[gi*8+u][tl]);
      *(bf16x8*)(row + ((gi^s7)<<3)) = v;
    } else if(gi == 16){
      v[0] = f2bf(tile[128][tl]);
      #pragma unroll
      for(int u=1;u<8;u++) v[u] = 0;
      *(bf16x8*)(row + (16<<3)) = v;
    } else {
      #pragma unroll
      for(int u=0;u<8;u++) v[u] = 0;
      *(bf16x8*)(row + (gi<<3)) = v;
    }
  }
}

// ---- Y=Q@Z (written straight to YT bf16 swizzled), PZ=P@Z (fp32).
// grid (33,17) x 512 thr: 8 rows/block, in-block k-split x2, LDS reduce.
__global__ __launch_bounds__(512) void k_small(
    const float* __restrict__ Z, const float* __restrict__ P,
    const float* __restrict__ Q, short* __restrict__ YT,
    float* __restrict__ PZ){
  __shared__ float qs[8][132], ps[8][132];
  __shared__ float red[16*256];
  const int tid = threadIdx.x, tx = tid&255, kg = tid>>8;
  const int r0 = blockIdx.y*8;
  for(int i=tid;i<8*129;i+=512){
    int rr=i/129, cc=i-rr*129;
    float qv=0.f, pv=0.f;
    if(r0+rr<D){ qv=Q[(r0+rr)*D+cc]; pv=P[(r0+rr)*D+cc]; }
    qs[rr][cc]=qv; ps[rr][cc]=pv;
  }
  __syncthreads();
  const int t = blockIdx.x*256 + tx;
  const bool valid = (t < N1);
  const int tc = valid ? t : (N1-1);
  const float* zp = Z + tc;
  float ay[8], ap[8];
  #pragma unroll
  for(int rr=0;rr<8;rr++){ ay[rr]=0.f; ap[rr]=0.f; }
  const int kbeg = kg ? 65 : 0, kend = kg ? 129 : 65;
  for(int k=kbeg;k<kend;k++){
    float z = zp[(size_t)k*N1];
    #pragma unroll
    for(int rr=0;rr<8;rr++){
      ay[rr] = fmaf(qs[rr][k], z, ay[rr]);
      ap[rr] = fmaf(ps[rr][k], z, ap[rr]);
    }
  }
  if(kg==1){
    #pragma unroll
    for(int rr=0;rr<8;rr++){
      red[rr*256+tx]     = ay[rr];
      red[(8+rr)*256+tx] = ap[rr];
    }
  }
  __syncthreads();
  if(kg==0){
    #pragma unroll
    for(int rr=0;rr<8;rr++){
      ay[rr] += red[rr*256+tx];
      ap[rr] += red[(8+rr)*256+tx];
    }
    // YT row t: this block's 8 m-values form exactly one 16B chunk gc=r0>>3
    short* row = YT + (size_t)t*KP;
    const int s7 = t&7;
    const int gc = r0>>3;
    bf16x8 v;
    #pragma unroll
    for(int u=0;u<8;u++) v[u] = f2bf(valid ? ay[u] : 0.f);
    if(gc < 16){
      *(bf16x8*)(row + ((gc^s7)<<3)) = v;
    } else {
      *(bf16x8*)(row + (16<<3)) = v;          // m=128..135 (only m=128 nonzero)
      bf16x8 zv;
      #pragma unroll
      for(int u=0;u<8;u++) zv[u]=0;
      *(bf16x8*)(row + (17<<3)) = zv;
      *(bf16x8*)(row + (18<<3)) = zv;
      *(bf16x8*)(row + (19<<3)) = zv;
    }
    // PZ fp32 rows r0..r0+7 (coalesced over t)
    #pragma unroll
    for(int rr=0;rr<8;rr++){
      int r=r0+rr;
      if(r<D) PZ[(size_t)r*WSTR + t] = valid ? ap[rr] : 0.f;
    }
  }
}

// ---- W[d,j] = PZ[d,j] + 0.9*W[d,j+1] (256-tap truncation at 16-chunk heads)
__global__ void k_scan(const float* __restrict__ PZ, float* __restrict__ W){
  __shared__ float s[2376];
  int d = blockIdx.y;
  int base = blockIdx.x*2048;
  for(int i=threadIdx.x;i<2304;i+=128){
    int j = base+i;
    s[i + (i>>5)] = (j<NN)? PZ[(size_t)d*WSTR + j] : 0.f;
  }
  __syncthreads();
  int t = threadIdx.x;
  int jh = t*16+15;
  float acc = 0.f, f = 1.f;
  for(int k=0;k<256;k++){ int a = jh+k; acc = fmaf(f, s[a+(a>>5)], acc); f *= 0.9f; }
  float wv[16];
  wv[15] = acc;
  #pragma unroll
  for(int r=14;r>=0;r--){ int a = t*16+r; wv[r] = fmaf(0.9f, wv[r+1], s[a+(a>>5)]); }
  float* out = W + (size_t)d*WSTR + base + t*16;
  #pragma unroll
  for(int r=0;r<16;r+=4) *(f32x4*)(out+r) = (f32x4){wv[r],wv[r+1],wv[r+2],wv[r+3]};
}

// ---- S[i] = sum over 33 jtb partials
__global__ void k_ssum(const float* __restrict__ S_part, float* __restrict__ S,
                       int i_base, int count){
  int idx = blockIdx.x*256+threadIdx.x;
  if(idx>=count) return;
  int i = i_base + idx;
  float s=0.f;
  #pragma unroll 3
  for(int jtb=0;jtb<33;jtb++) s += S_part[(size_t)jtb*WSTR + i];
  S[i]=s;
}

// ---- V tiles: Vt[it][144 d][128 pos] bf16 (pos -> true i via tau), XOR-swizzled rows
__global__ void k_v(const float* __restrict__ W, const float* __restrict__ S,
                    short* __restrict__ Vt, int tile0){
  int idx = blockIdx.x*256+threadIdx.x;
  int l = idx/18432, rem = idx - l*18432;
  int d = rem>>7, ci = rem&127;
  int it = tile0 + l;
  int i = it*128 + tau(ci);
  float v = (d<=128)? W[(size_t)d*WSTR + i]/S[i] : 0.f;
  int gs = (ci>>3) ^ (d&7);
  Vt[(size_t)it*18432 + (d<<7) + gs*8 + (ci&7)] = f2bf(v);
}

// ---- pass0: X-tile [128 i][256 j] via mfma(Z,Y); E stored bf16 16B/lane (UNSWIZZLED rows);
//      S via latency-free LDS partial grid (no shfl chains, no atomics)
__global__ __launch_bounds__(512,4) void k_qke(
    const short* __restrict__ ZT, const short* __restrict__ YT,
    short* __restrict__ Ebuf, float* __restrict__ S_part, int tile0, int ITC, int nwg){
  __shared__ short zt[128*KP];      // 40960 B
  __shared__ short sp[32*132];      // 8448 B: bf16 pair-partials [wl][i]
  const int tid=threadIdx.x, w=tid>>6, lane=tid&63, g=lane>>4, lm=lane&15;
  // bijective XCD swizzle: consecutive wg (same jtb, consecutive itl) share an XCD
  int bid = blockIdx.x;
  int qq = nwg>>3, rr8 = nwg&7, xcd = bid&7, ix = bid>>3;
  int wg = (xcd<rr8 ? xcd*(qq+1) : rr8*(qq+1)+(xcd-rr8)*qq) + ix;
  const int jtb = wg/ITC, itl = wg - jtb*ITC;
  const int it = tile0 + itl;
  const int sx = lm&7;

  // stage Z tile (contiguous 40960B)
  const short* ztg = ZT + (size_t)it*(128*KP);
  #pragma unroll
  for(int q=0;q<5;q++){
    int off = (q*512 + tid)*8;
    GLOAD_LDS16(ztg + off, zt + off);
  }

  // B-frags: Y rows = X columns j (col = lm, k consecutive)
  bf16x8 b[2][5];
  #pragma unroll
  for(int p=0;p<2;p++){
    int jr = jtb*256 + w*32 + p*16 + lm;
    const short* rp = YT + (size_t)jr*KP;
    #pragma unroll
    for(int kk=0;kk<4;kk++) b[p][kk] = *(const bf16x8*)(rp + (((kk*4+g)^sx)<<3));
    b[p][4] = *(const bf16x8*)(rp + ((16+g)<<3));
  }
  const int jl0 = w*32 + lm, jl1 = jl0 + 16;
  const bool jv0 = (jtb*256 + jl0) < N1;
  const bool jv1 = (jtb*256 + jl1) < N1;
  short* ep0 = Ebuf + ((size_t)(jtb*2 + (jl0>>7))*ITC + itl)*16384 + (jl0&127)*128;
  short* ep1 = Ebuf + ((size_t)(jtb*2 + (jl1>>7))*ITC + itl)*16384 + (jl1&127)*128;
  const int wl = w*4 + (lm>>2);
  __syncthreads();

  #pragma unroll
  for(int p2=0;p2<4;p2++){
    const int ib0 = 2*p2, ib1 = ib0+1;
    f32x4 aA0={0.f,0.f,0.f,0.f}, aA1={0.f,0.f,0.f,0.f};
    f32x4 aB0={0.f,0.f,0.f,0.f}, aB1={0.f,0.f,0.f,0.f};
    const short* zpA = zt + (ib0*16+lm)*KP;
    const short* zpB = zt + (ib1*16+lm)*KP;
    #pragma unroll
    for(int kk=0;kk<4;kk++){
      bf16x8 fa = *(const bf16x8*)(zpA + (((kk*4+g)^sx)<<3));
      bf16x8 fb = *(const bf16x8*)(zpB + (((kk*4+g)^sx)<<3));
      aA0 = __builtin_amdgcn_mfma_f32_16x16x32_bf16(fa, b[0][kk], aA0, 0,0,0);
      aA1 = __builtin_amdgcn_mfma_f32_16x16x32_bf16(fa, b[1][kk], aA1, 0,0,0);
      aB0 = __builtin_amdgcn_mfma_f32_16x16x32_bf16(fb, b[0][kk], aB0, 0,0,0);
      aB1 = __builtin_amdgcn_mfma_f32_16x16x32_bf16(fb, b[1][kk], aB1, 0,0,0);
    }
    {
      bf16x8 fa = *(const bf16x8*)(zpA + ((16+g)<<3));
      bf16x8 fb = *(const bf16x8*)(zpB + ((16+g)<<3));
      aA0 = __builtin_amdgcn_mfma_f32_16x16x32_bf16(fa, b[0][4], aA0, 0,0,0);
      aA1 = __builtin_amdgcn_mfma_f32_16x16x32_bf16(fa, b[1][4], aA1, 0,0,0);
      aB0 = __builtin_amdgcn_mfma_f32_16x16x32_bf16(fb, b[0][4], aB0, 0,0,0);
      aB1 = __builtin_amdgcn_mfma_f32_16x16x32_bf16(fb, b[1][4], aB1, 0,0,0);
    }
    float eA0[4], eA1[4], eB0[4], eB1[4];
    #pragma unroll
    for(int r=0;r<4;r++){
      eA0[r] = jv0 ? __expf(aA0[r]) : 0.f;
      eA1[r] = jv1 ? __expf(aA1[r]) : 0.f;
      eB0[r] = jv0 ? __expf(aB0[r]) : 0.f;
      eB1[r] = jv1 ? __expf(aB1[r]) : 0.f;
    }
    // coalesced 16B stores, unswizzled: pos = p2*32 + g*8 + (ib&1)*4 + r
    const int c0 = p2*4 + g;
    *(u32x4*)(ep0 + (c0<<3)) =
      (u32x4){cvtpk(eA0[0],eA0[1]), cvtpk(eA0[2],eA0[3]), cvtpk(eB0[0],eB0[1]), cvtpk(eB0[2],eB0[3])};
    *(u32x4*)(ep1 + (c0<<3)) =
      (u32x4){cvtpk(eA1[0],eA1[1]), cvtpk(eA1[2],eA1[3]), cvtpk(eB1[0],eB1[1]), cvtpk(eB1[2],eB1[3])};
    // S partials: 2-hop lm-fold then one b64 LDS write per (p2, half) — no chains/atomics
    float vA[4], vB[4];
    #pragma unroll
    for(int r=0;r<4;r++){
      float sa = eA0[r] + eA1[r];
      sa += __shfl_xor(sa,1); sa += __shfl_xor(sa,2);
      vA[r]=sa;
      float sb = eB0[r] + eB1[r];
      sb += __shfl_xor(sb,1); sb += __shfl_xor(sb,2);
      vB[r]=sb;
    }
    if((lm&3)==0){
      int i0 = p2*32 + g*4;
      *(u32x2*)(sp + wl*132 + i0)      = (u32x2){cvtpk(vA[0],vA[1]), cvtpk(vA[2],vA[3])};
      *(u32x2*)(sp + wl*132 + i0 + 16) = (u32x2){cvtpk(vB[0],vB[1]), cvtpk(vB[2],vB[3])};
    }
  }
  __syncthreads();
  // final reduce: thread (i=tid>>2, q=tid&3) sums 8 wl slots, 2-shfl fold over q
  {
    int i = tid>>2, q = tid&3;
    float s=0.f;
    #pragma unroll
    for(int k=0;k<8;k++) s += bf2f((unsigned short)sp[(q*8+k)*132 + i]);
    s += __shfl_xor(s,1); s += __shfl_xor(s,2);
    if(q==0) S_part[(size_t)jtb*WSTR + it*128 + i] = s;
  }
}

// ---- pass1: part[ks][144 d][128 j] = V @ E. V-only LDS dbuf (72KB, 2 blocks/CU);
//      E direct global->reg, 2-deep pipeline.
__global__ __launch_bounds__(512,4) void k_pv(
    const short* __restrict__ Ebuf, const short* __restrict__ Vt,
    float* __restrict__ part, int ITC, int tile0, int ks_base, int nT){
  __shared__ short vlds[2][18432];
  const int tid=threadIdx.x, w=tid>>6, lane=tid&63, g=lane>>4, lm=lane&15;
  const int jt = blockIdx.x;
  const int ks = ks_base + blockIdx.y;
  const int t0l = blockIdx.y*nT;
  const int sx = lm&7;

  f32x4 acc[9];
  #pragma unroll
  for(int m=0;m<9;m++) acc[m] = (f32x4){0.f,0.f,0.f,0.f};

  auto stageV = [&](int buf, int tl){
    const short* vg = Vt + (size_t)(tile0 + tl)*18432;
    short* vb = &vlds[buf][0];
    #pragma unroll
    for(int q=0;q<5;q++){
      int idx = q*512 + tid;
      if(idx < 2304) GLOAD_LDS16(vg + idx*8, vb + idx*8);
    }
  };
  const short* erow = Ebuf + (size_t)jt*ITC*16384 + (w*16+lm)*128 + (g<<3);
  auto loadE = [&](bf16x8 (&e)[4], int tl){
    const short* ep = erow + (size_t)tl*16384;
    #pragma unroll
    for(int kk=0;kk<4;kk++) e[kk] = *(const bf16x8*)(ep + (kk<<5));
  };
  auto compute = [&](int buf, bf16x8 (&e)[4]){
    const short* vb = &vlds[buf][0];
    #pragma unroll
    for(int kk=0;kk<4;kk++){
      int go = ((kk*4+g)^sx)<<3;
      #pragma unroll
      for(int m=0;m<9;m++){
        bf16x8 av = *(const bf16x8*)(vb + ((m*16+lm)<<7) + go);
        acc[m] = __builtin_amdgcn_mfma_f32_16x16x32_bf16(av, e[kk], acc[m], 0,0,0);
      }
    }
  };

  bf16x8 eA[4], eB[4];
  stageV(0, t0l);
  loadE(eA, t0l);

  for(int t=0; t<nT; t+=2){
    __syncthreads();                       // drains tile-t V stage + eA loads; frees vlds[1]
    if(t+1<nT){ stageV(1, t0l+t+1); loadE(eB, t0l+t+1); }
    compute(0, eA);
    __syncthreads();                       // drains tile-(t+1) V stage + eB loads; frees vlds[0]
    if(t+2<nT){ stageV(0, t0l+t+2); loadE(eA, t0l+t+2); }
    if(t+1<nT) compute(1, eB);
  }

  float* pb = part + (size_t)ks*144*PSTR;
  const int j = jt*128 + w*16 + lm;
  #pragma unroll
  for(int m=0;m<9;m++){
    #pragma unroll
    for(int r=0;r<4;r++)
      pb[(size_t)(m*16+g*4+r)*PSTR + j] = acc[m][r];
  }
}

// ---- out = Zc + INV_N * sum_ks part[ks]
__global__ void k_out(const float* __restrict__ Zc, const float* __restrict__ part,
                      float* __restrict__ out, int st){
  int idx = blockIdx.x*256+threadIdx.x;
  if(idx >= 129*2049) return;
  int d = idx/2049, jq = idx - d*2049;
  int j0 = jq*4;
  float s0=0.f,s1=0.f,s2=0.f,s3=0.f;
  for(int ks=0;ks<st;ks++){
    f32x4 v = *(const f32x4*)(part + (size_t)ks*144*PSTR + (size_t)d*PSTR + j0);
    s0+=v[0]; s1+=v[1]; s2+=v[2]; s3+=v[3];
  }
  const float* zr = Zc + (size_t)d*N1;
  float* orow = out + (size_t)d*N1;
  float sv[4] = {s0,s1,s2,s3};
  #pragma unroll
  for(int u=0;u<4;u++){
    int j = j0+u;
    if(j < N1) orow[j] = zr[j] + INV_N*sv[u];
  }
}

extern "C" void kernel_launch(void* const* d_in, const int* in_sizes, int n_in,
                              void* d_out, int out_size, void* d_ws, size_t ws_size,
                              hipStream_t stream){
  (void)in_sizes; (void)n_in; (void)out_size;
  const float* Zin=(const float*)d_in[0];
  const float* Pm =(const float*)d_in[1];
  const float* Qm =(const float*)d_in[2];
  float* out=(float*)d_out;

  // config ladder: c chunks of i-tiles; k_pv grid y = ksPC stripes per chunk; st = c*ksPC
  const size_t fixed = 2*(size_t)D*N1*4 + 2*(size_t)D*WSTR*4 + (size_t)WSTR*4
                     + (size_t)33*WSTR*4
                     + 2*(size_t)TROWS*KP*2 + (size_t)64*18432*2 + 16*4096;
  int c=8, ksPC=1;
  {
    const int cs[5] = {1,1,2,4,8};
    const int kp[5] = {8,4,2,1,1};
    for(int k=0;k<5;k++){
      int stc = cs[k]*kp[k];
      size_t need = fixed + (size_t)stc*144*PSTR*4 + (size_t)66*(64/cs[k])*16384*2;
      if(need <= ws_size){ c=cs[k]; ksPC=kp[k]; break; }
    }
  }
  const int ITC = 64/c, nT = ITC/ksPC, st = c*ksPC;

  char* base=(char*)d_ws;
  size_t off=0;
  auto alloc=[&](size_t b)->void*{ void* p=base+off; off=(off+b+255)&~(size_t)255; return p; };
  float* Z0  =(float*)alloc((size_t)D*N1*4);
  float* Z1  =(float*)alloc((size_t)D*N1*4);
  float* PZ  =(float*)alloc((size_t)D*WSTR*4);
  float* Wf  =(float*)alloc((size_t)D*WSTR*4);
  float* S   =(float*)alloc((size_t)WSTR*4);
  float* Sp  =(float*)alloc((size_t)33*WSTR*4);
  short* ZT  =(short*)alloc((size_t)TROWS*KP*2);
  short* YT  =(short*)alloc((size_t)TROWS*KP*2);
  short* Vt  =(short*)alloc((size_t)64*18432*2);
  float* part=(float*)alloc((size_t)st*144*PSTR*4);
  short* Ebuf=(short*)alloc((size_t)66*ITC*16384*2);

  const float* Zc=Zin;
  for(int l=0;l<4;l++){
    float* Zn = (l==3)? out : ((l&1)? Z1:Z0);
    k_small<<<dim3(33,17),dim3(512),0,stream>>>(Zc,Pm,Qm,YT,PZ);
    k_tr<<<dim3(132),dim3(256),0,stream>>>(Zc,ZT,N1);
    k_scan<<<dim3(4,D),dim3(128),0,stream>>>(PZ,Wf);
    for(int ch=0; ch<c; ch++){
      int tile0 = ch*ITC;
      int nwg = 33*ITC;
      k_qke<<<dim3(nwg),dim3(512),0,stream>>>(ZT,YT,Ebuf,Sp,tile0,ITC,nwg);
      k_ssum<<<dim3((ITC*128+255)/256),dim3(256),0,stream>>>(Sp,S,tile0*128,ITC*128);
      k_v<<<dim3(ITC*72),dim3(256),0,stream>>>(Wf,S,Vt,tile0);
      k_pv<<<dim3(65,ksPC),dim3(512),0,stream>>>(Ebuf,Vt,part,ITC,tile0,ch*ksPC,nT);
    }
    k_out<<<dim3(1033),dim3(256),0,stream>>>(Zc,part,Zn,st);
    Zc=Zn;
  }
}

// Round 14
// 590.400 us; speedup vs baseline: 3.6273x; 1.0605x over previous
//
#include <hip/hip_runtime.h>

#define D 129
#define N1 8193
#define NN 8192
#define INV_N (1.0f/8192.0f)
#define OUT_SCALE (1.0f/(8192.0f*512.0f))   // INV_N / (V_SCALE/E_SCALE = 4096/8)
#define WSTR 8448        // fp32 row stride for PZ / W
#define KP 160           // padded K (129 -> 160, cols 129..159 zero)
#define TROWS 8448       // rows in ZT/YT (multiple of 256)
#define PSTR 8320        // part row stride (fp32)

typedef __attribute__((ext_vector_type(8))) short bf16x8;
typedef __attribute__((ext_vector_type(4))) float f32x4;
typedef __attribute__((ext_vector_type(2))) unsigned u32x2;
typedef long long i64;

__device__ __forceinline__ short f2bf(float x){
  unsigned u = __float_as_uint(x);
  unsigned r = (u + 0x7fffu + ((u>>16)&1u)) >> 16;
  return (short)r;
}

__device__ __forceinline__ unsigned cvtpk(float a, float b){
  unsigned r; asm("v_cvt_pk_bf16_f32 %0, %1, %2" : "=v"(r) : "v"(a), "v"(b)); return r;
}

__device__ __forceinline__ float bf2f(unsigned short v){
  return __uint_as_float(((unsigned)v)<<16);
}

// pack 4 floats -> 4 fp8 (e4m3) bytes in an int
__device__ __forceinline__ int pk_fp8x4(float a, float b, float c, float d){
  int r = __builtin_amdgcn_cvt_pk_fp8_f32(a, b, 0, false);
  r = __builtin_amdgcn_cvt_pk_fp8_f32(c, d, r, true);
  return r;
}

#define GLOAD_LDS16(gp, lp) __builtin_amdgcn_global_load_lds( \
    (const __attribute__((address_space(1))) void*)(gp),      \
    (__attribute__((address_space(3))) void*)(lp), 16, 0, 0)

// E-row i-permutation: storage position pos -> true i
__device__ __forceinline__ int tau(int pos){
  return (pos & 96) + ((pos & 4) << 2) + ((pos & 24) >> 1) + (pos & 3);
}

// ---- transpose fp32 [129][N1] -> bf16 swizzled [t][160]; col 128 = row128, 129..159 = 0
__global__ void k_tr(const float* __restrict__ src, short* __restrict__ dst, int tmax){
  __shared__ float tile[129][65];
  int t0 = blockIdx.x*64, tid = threadIdx.x;
  for(int idx=tid; idx<129*64; idx+=256){
    int d = idx>>6, c = idx&63;
    tile[d][c] = (t0+c < tmax)? src[(size_t)d*N1 + t0+c] : 0.f;
  }
  __syncthreads();
  int q = tid&3, tl = tid>>2;
  int t = t0 + tl;
  short* row = dst + (size_t)t*KP;
  int s7 = t&7;
  #pragma unroll
  for(int g5=0; g5<5; g5++){
    int gi = q*5 + g5;
    bf16x8 v;
    if(gi < 16){
      #pragma unroll
      for(int u=0;u<8;u++) v[u] = f2bf(tile[gi*8+u][tl]);
      *(bf16x8*)(row + ((gi^s7)<<3)) = v;
    } else if(gi == 16){
      v[0] = f2bf(tile[128][tl]);
      #pragma unroll
      for(int u=1;u<8;u++) v[u] = 0;
      *(bf16x8*)(row + (16<<3)) = v;
    } else {
      #pragma unroll
      for(int u=0;u<8;u++) v[u] = 0;
      *(bf16x8*)(row + (gi<<3)) = v;
    }
  }
}

// ---- Y=Q@Z (written straight to YT bf16 swizzled), PZ=P@Z (fp32).
__global__ __launch_bounds__(512) void k_small(
    const float* __restrict__ Z, const float* __restrict__ P,
    const float* __restrict__ Q, short* __restrict__ YT,
    float* __restrict__ PZ){
  __shared__ float qs[8][132], ps[8][132];
  __shared__ float red[16*256];
  const int tid = threadIdx.x, tx = tid&255, kg = tid>>8;
  const int r0 = blockIdx.y*8;
  for(int i=tid;i<8*129;i+=512){
    int rr=i/129, cc=i-rr*129;
    float qv=0.f, pv=0.f;
    if(r0+rr<D){ qv=Q[(r0+rr)*D+cc]; pv=P[(r0+rr)*D+cc]; }
    qs[rr][cc]=qv; ps[rr][cc]=pv;
  }
  __syncthreads();
  const int t = blockIdx.x*256 + tx;
  const bool valid = (t < N1);
  const int tc = valid ? t : (N1-1);
  const float* zp = Z + tc;
  float ay[8], ap[8];
  #pragma unroll
  for(int rr=0;rr<8;rr++){ ay[rr]=0.f; ap[rr]=0.f; }
  const int kbeg = kg ? 65 : 0, kend = kg ? 129 : 65;
  for(int k=kbeg;k<kend;k++){
    float z = zp[(size_t)k*N1];
    #pragma unroll
    for(int rr=0;rr<8;rr++){
      ay[rr] = fmaf(qs[rr][k], z, ay[rr]);
      ap[rr] = fmaf(ps[rr][k], z, ap[rr]);
    }
  }
  if(kg==1){
    #pragma unroll
    for(int rr=0;rr<8;rr++){
      red[rr*256+tx]     = ay[rr];
      red[(8+rr)*256+tx] = ap[rr];
    }
  }
  __syncthreads();
  if(kg==0){
    #pragma unroll
    for(int rr=0;rr<8;rr++){
      ay[rr] += red[rr*256+tx];
      ap[rr] += red[(8+rr)*256+tx];
    }
    short* row = YT + (size_t)t*KP;
    const int s7 = t&7;
    const int gc = r0>>3;
    bf16x8 v;
    #pragma unroll
    for(int u=0;u<8;u++) v[u] = f2bf(valid ? ay[u] : 0.f);
    if(gc < 16){
      *(bf16x8*)(row + ((gc^s7)<<3)) = v;
    } else {
      *(bf16x8*)(row + (16<<3)) = v;
      bf16x8 zv;
      #pragma unroll
      for(int u=0;u<8;u++) zv[u]=0;
      *(bf16x8*)(row + (17<<3)) = zv;
      *(bf16x8*)(row + (18<<3)) = zv;
      *(bf16x8*)(row + (19<<3)) = zv;
    }
    #pragma unroll
    for(int rr=0;rr<8;rr++){
      int r=r0+rr;
      if(r<D) PZ[(size_t)r*WSTR + t] = valid ? ap[rr] : 0.f;
    }
  }
}

// ---- W[d,j] = PZ[d,j] + 0.9*W[d,j+1] (256-tap truncation at 16-chunk heads)
__global__ void k_scan(const float* __restrict__ PZ, float* __restrict__ W){
  __shared__ float s[2376];
  int d = blockIdx.y;
  int base = blockIdx.x*2048;
  for(int i=threadIdx.x;i<2304;i+=128){
    int j = base+i;
    s[i + (i>>5)] = (j<NN)? PZ[(size_t)d*WSTR + j] : 0.f;
  }
  __syncthreads();
  int t = threadIdx.x;
  int jh = t*16+15;
  float acc = 0.f, f = 1.f;
  for(int k=0;k<256;k++){ int a = jh+k; acc = fmaf(f, s[a+(a>>5)], acc); f *= 0.9f; }
  float wv[16];
  wv[15] = acc;
  #pragma unroll
  for(int r=14;r>=0;r--){ int a = t*16+r; wv[r] = fmaf(0.9f, wv[r+1], s[a+(a>>5)]); }
  float* out = W + (size_t)d*WSTR + base + t*16;
  #pragma unroll
  for(int r=0;r<16;r+=4) *(f32x4*)(out+r) = (f32x4){wv[r],wv[r+1],wv[r+2],wv[r+3]};
}

// ---- S[i] = sum over 33 jtb partials
__global__ void k_ssum(const float* __restrict__ S_part, float* __restrict__ S,
                       int i_base, int count){
  int idx = blockIdx.x*256+threadIdx.x;
  if(idx>=count) return;
  int i = i_base + idx;
  float s=0.f;
  #pragma unroll 3
  for(int jtb=0;jtb<33;jtb++) s += S_part[(size_t)jtb*WSTR + i];
  S[i]=s;
}

// ---- V tiles fp8: Vt[it][144 d][128 pos] bytes (pos->i via tau), V*4096, XOR-swz chunks
__global__ void k_v(const float* __restrict__ W, const float* __restrict__ S,
                    unsigned char* __restrict__ Vt, int tile0){
  int idx = blockIdx.x*256+threadIdx.x;
  int l = idx/4608, rem = idx - l*4608;       // 144*32 = 4608 threads per tile
  int d = rem>>5, c4 = rem&31;
  int ci0 = c4<<2;
  int it = tile0 + l;
  int i0 = it*128 + tau(ci0);
  float v0=0.f,v1=0.f,v2=0.f,v3=0.f;
  if(d<=128){
    f32x4 w4 = *(const f32x4*)(W + (size_t)d*WSTR + i0);
    f32x4 s4 = *(const f32x4*)(S + i0);
    v0 = w4[0]/s4[0]*4096.f; v1 = w4[1]/s4[1]*4096.f;
    v2 = w4[2]/s4[2]*4096.f; v3 = w4[3]/s4[3]*4096.f;
  }
  int gs = (ci0>>3) ^ (d&7);
  int addr = (int)((size_t)0) + (d<<7) + gs*8 + (ci0&7);
  *(int*)(Vt + (size_t)it*18432 + addr) = pk_fp8x4(v0,v1,v2,v3);
}

// ---- pass0: X-tile [128 i][256 j] via mfma(Z,Y); E stored fp8 (E/8), 8B/lane coalesced;
//      S via LDS partial grid (true fp32 e sums)
__global__ __launch_bounds__(512,4) void k_qke(
    const short* __restrict__ ZT, const short* __restrict__ YT,
    unsigned char* __restrict__ Ebuf, float* __restrict__ S_part, int tile0, int ITC, int nwg){
  __shared__ short zt[128*KP];      // 40960 B
  __shared__ short sp[32*132];      // 8448 B
  const int tid=threadIdx.x, w=tid>>6, lane=tid&63, g=lane>>4, lm=lane&15;
  int bid = blockIdx.x;
  int qq = nwg>>3, rr8 = nwg&7, xcd = bid&7, ix = bid>>3;
  int wg = (xcd<rr8 ? xcd*(qq+1) : rr8*(qq+1)+(xcd-rr8)*qq) + ix;
  const int jtb = wg/ITC, itl = wg - jtb*ITC;
  const int it = tile0 + itl;
  const int sx = lm&7;

  const short* ztg = ZT + (size_t)it*(128*KP);
  #pragma unroll
  for(int q=0;q<5;q++){
    int off = (q*512 + tid)*8;
    GLOAD_LDS16(ztg + off, zt + off);
  }

  bf16x8 b[2][5];
  #pragma unroll
  for(int p=0;p<2;p++){
    int jr = jtb*256 + w*32 + p*16 + lm;
    const short* rp = YT + (size_t)jr*KP;
    #pragma unroll
    for(int kk=0;kk<4;kk++) b[p][kk] = *(const bf16x8*)(rp + (((kk*4+g)^sx)<<3));
    b[p][4] = *(const bf16x8*)(rp + ((16+g)<<3));
  }
  const int jl0 = w*32 + lm, jl1 = jl0 + 16;
  const bool jv0 = (jtb*256 + jl0) < N1;
  const bool jv1 = (jtb*256 + jl1) < N1;
  unsigned char* ep0 = Ebuf + ((size_t)(jtb*2 + (jl0>>7))*ITC + itl)*16384 + (jl0&127)*128;
  unsigned char* ep1 = Ebuf + ((size_t)(jtb*2 + (jl1>>7))*ITC + itl)*16384 + (jl1&127)*128;
  const int wl = w*4 + (lm>>2);
  __syncthreads();

  #pragma unroll
  for(int p2=0;p2<4;p2++){
    const int ib0 = 2*p2, ib1 = ib0+1;
    f32x4 aA0={0.f,0.f,0.f,0.f}, aA1={0.f,0.f,0.f,0.f};
    f32x4 aB0={0.f,0.f,0.f,0.f}, aB1={0.f,0.f,0.f,0.f};
    const short* zpA = zt + (ib0*16+lm)*KP;
    const short* zpB = zt + (ib1*16+lm)*KP;
    #pragma unroll
    for(int kk=0;kk<4;kk++){
      bf16x8 fa = *(const bf16x8*)(zpA + (((kk*4+g)^sx)<<3));
      bf16x8 fb = *(const bf16x8*)(zpB + (((kk*4+g)^sx)<<3));
      aA0 = __builtin_amdgcn_mfma_f32_16x16x32_bf16(fa, b[0][kk], aA0, 0,0,0);
      aA1 = __builtin_amdgcn_mfma_f32_16x16x32_bf16(fa, b[1][kk], aA1, 0,0,0);
      aB0 = __builtin_amdgcn_mfma_f32_16x16x32_bf16(fb, b[0][kk], aB0, 0,0,0);
      aB1 = __builtin_amdgcn_mfma_f32_16x16x32_bf16(fb, b[1][kk], aB1, 0,0,0);
    }
    {
      bf16x8 fa = *(const bf16x8*)(zpA + ((16+g)<<3));
      bf16x8 fb = *(const bf16x8*)(zpB + ((16+g)<<3));
      aA0 = __builtin_amdgcn_mfma_f32_16x16x32_bf16(fa, b[0][4], aA0, 0,0,0);
      aA1 = __builtin_amdgcn_mfma_f32_16x16x32_bf16(fa, b[1][4], aA1, 0,0,0);
      aB0 = __builtin_amdgcn_mfma_f32_16x16x32_bf16(fb, b[0][4], aB0, 0,0,0);
      aB1 = __builtin_amdgcn_mfma_f32_16x16x32_bf16(fb, b[1][4], aB1, 0,0,0);
    }
    float eA0[4], eA1[4], eB0[4], eB1[4];
    #pragma unroll
    for(int r=0;r<4;r++){
      eA0[r] = jv0 ? __expf(aA0[r]) : 0.f;
      eA1[r] = jv1 ? __expf(aA1[r]) : 0.f;
      eB0[r] = jv0 ? __expf(aB0[r]) : 0.f;
      eB1[r] = jv1 ? __expf(aB1[r]) : 0.f;
    }
    // fp8 stores (E/8): 8B per ep, pos = p2*32 + g*8 + (ib&1)*4 + r
    const int c0 = p2*4 + g;
    *(u32x2*)(ep0 + (c0<<3)) = (u32x2){
      (unsigned)pk_fp8x4(eA0[0]*0.125f, eA0[1]*0.125f, eA0[2]*0.125f, eA0[3]*0.125f),
      (unsigned)pk_fp8x4(eB0[0]*0.125f, eB0[1]*0.125f, eB0[2]*0.125f, eB0[3]*0.125f)};
    *(u32x2*)(ep1 + (c0<<3)) = (u32x2){
      (unsigned)pk_fp8x4(eA1[0]*0.125f, eA1[1]*0.125f, eA1[2]*0.125f, eA1[3]*0.125f),
      (unsigned)pk_fp8x4(eB1[0]*0.125f, eB1[1]*0.125f, eB1[2]*0.125f, eB1[3]*0.125f)};
    float vA[4], vB[4];
    #pragma unroll
    for(int r=0;r<4;r++){
      float sa = eA0[r] + eA1[r];
      sa += __shfl_xor(sa,1); sa += __shfl_xor(sa,2);
      vA[r]=sa;
      float sb = eB0[r] + eB1[r];
      sb += __shfl_xor(sb,1); sb += __shfl_xor(sb,2);
      vB[r]=sb;
    }
    if((lm&3)==0){
      int i0 = p2*32 + g*4;
      *(u32x2*)(sp + wl*132 + i0)      = (u32x2){cvtpk(vA[0],vA[1]), cvtpk(vA[2],vA[3])};
      *(u32x2*)(sp + wl*132 + i0 + 16) = (u32x2){cvtpk(vB[0],vB[1]), cvtpk(vB[2],vB[3])};
    }
  }
  __syncthreads();
  {
    int i = tid>>2, q = tid&3;
    float s=0.f;
    #pragma unroll
    for(int k=0;k<8;k++) s += bf2f((unsigned short)sp[(q*8+k)*132 + i]);
    s += __shfl_xor(s,1); s += __shfl_xor(s,2);
    if(q==0) S_part[(size_t)jtb*WSTR + it*128 + i] = s;
  }
}

// ---- pass1: part[ks][144 d][128 j] = V @ E (fp8 mfma). V-only LDS dbuf; E global->reg.
__global__ __launch_bounds__(512,4) void k_pv(
    const unsigned char* __restrict__ Ebuf, const unsigned char* __restrict__ Vt,
    float* __restrict__ part, int ITC, int tile0, int ks_base, int nT){
  __shared__ unsigned char vlds[2][18432];
  const int tid=threadIdx.x, w=tid>>6, lane=tid&63, g=lane>>4, lm=lane&15;
  const int jt = blockIdx.x;
  const int ks = ks_base + blockIdx.y;
  const int t0l = blockIdx.y*nT;
  const int sx = lm&7;

  f32x4 acc[9];
  #pragma unroll
  for(int m=0;m<9;m++) acc[m] = (f32x4){0.f,0.f,0.f,0.f};

  auto stageV = [&](int buf, int tl){
    const unsigned char* vg = Vt + (size_t)(tile0 + tl)*18432;
    unsigned char* vb = &vlds[buf][0];
    #pragma unroll
    for(int q=0;q<3;q++){
      int idx = q*512 + tid;
      if(idx < 1152) GLOAD_LDS16(vg + idx*16, vb + idx*16);
    }
  };
  const unsigned char* erow = Ebuf + (size_t)jt*ITC*16384 + (w*16+lm)*128 + (g<<3);
  auto loadE = [&](i64 (&e)[4], int tl){
    const unsigned char* ep = erow + (size_t)tl*16384;
    #pragma unroll
    for(int kk=0;kk<4;kk++) e[kk] = *(const i64*)(ep + (kk<<5));
  };
  auto compute = [&](int buf, i64 (&e)[4]){
    const unsigned char* vb = &vlds[buf][0];
    #pragma unroll
    for(int kk=0;kk<4;kk++){
      int go = ((kk*4+g)^sx)<<3;
      #pragma unroll
      for(int m=0;m<9;m++){
        i64 av = *(const i64*)(vb + ((m*16+lm)<<7) + go);
        acc[m] = __builtin_amdgcn_mfma_f32_16x16x32_fp8_fp8(av, e[kk], acc[m], 0,0,0);
      }
    }
  };

  i64 eA[4], eB[4];
  stageV(0, t0l);
  loadE(eA, t0l);

  for(int t=0; t<nT; t+=2){
    __syncthreads();
    if(t+1<nT){ stageV(1, t0l+t+1); loadE(eB, t0l+t+1); }
    compute(0, eA);
    __syncthreads();
    if(t+2<nT){ stageV(0, t0l+t+2); loadE(eA, t0l+t+2); }
    if(t+1<nT) compute(1, eB);
  }

  float* pb = part + (size_t)ks*144*PSTR;
  const int j = jt*128 + w*16 + lm;
  #pragma unroll
  for(int m=0;m<9;m++){
    #pragma unroll
    for(int r=0;r<4;r++)
      pb[(size_t)(m*16+g*4+r)*PSTR + j] = acc[m][r];
  }
}

// ---- out = Zc + OUT_SCALE * sum_ks part[ks]
__global__ void k_out(const float* __restrict__ Zc, const float* __restrict__ part,
                      float* __restrict__ out, int st){
  int idx = blockIdx.x*256+threadIdx.x;
  if(idx >= 129*2049) return;
  int d = idx/2049, jq = idx - d*2049;
  int j0 = jq*4;
  float s0=0.f,s1=0.f,s2=0.f,s3=0.f;
  for(int ks=0;ks<st;ks++){
    f32x4 v = *(const f32x4*)(part + (size_t)ks*144*PSTR + (size_t)d*PSTR + j0);
    s0+=v[0]; s1+=v[1]; s2+=v[2]; s3+=v[3];
  }
  const float* zr = Zc + (size_t)d*N1;
  float* orow = out + (size_t)d*N1;
  float sv[4] = {s0,s1,s2,s3};
  #pragma unroll
  for(int u=0;u<4;u++){
    int j = j0+u;
    if(j < N1) orow[j] = zr[j] + OUT_SCALE*sv[u];
  }
}

extern "C" void kernel_launch(void* const* d_in, const int* in_sizes, int n_in,
                              void* d_out, int out_size, void* d_ws, size_t ws_size,
                              hipStream_t stream){
  (void)in_sizes; (void)n_in; (void)out_size;
  const float* Zin=(const float*)d_in[0];
  const float* Pm =(const float*)d_in[1];
  const float* Qm =(const float*)d_in[2];
  float* out=(float*)d_out;

  const size_t fixed = 2*(size_t)D*N1*4 + 2*(size_t)D*WSTR*4 + (size_t)WSTR*4
                     + (size_t)33*WSTR*4
                     + 2*(size_t)TROWS*KP*2 + (size_t)64*18432 + 16*4096;
  int c=8, ksPC=1;
  {
    const int cs[5] = {1,1,2,4,8};
    const int kp[5] = {8,4,2,1,1};
    for(int k=0;k<5;k++){
      int stc = cs[k]*kp[k];
      size_t need = fixed + (size_t)stc*144*PSTR*4 + (size_t)66*(64/cs[k])*16384;
      if(need <= ws_size){ c=cs[k]; ksPC=kp[k]; break; }
    }
  }
  const int ITC = 64/c, nT = ITC/ksPC, st = c*ksPC;

  char* base=(char*)d_ws;
  size_t off=0;
  auto alloc=[&](size_t b)->void*{ void* p=base+off; off=(off+b+255)&~(size_t)255; return p; };
  float* Z0  =(float*)alloc((size_t)D*N1*4);
  float* Z1  =(float*)alloc((size_t)D*N1*4);
  float* PZ  =(float*)alloc((size_t)D*WSTR*4);
  float* Wf  =(float*)alloc((size_t)D*WSTR*4);
  float* S   =(float*)alloc((size_t)WSTR*4);
  float* Sp  =(float*)alloc((size_t)33*WSTR*4);
  short* ZT  =(short*)alloc((size_t)TROWS*KP*2);
  short* YT  =(short*)alloc((size_t)TROWS*KP*2);
  unsigned char* Vt  =(unsigned char*)alloc((size_t)64*18432);
  float* part=(float*)alloc((size_t)st*144*PSTR*4);
  unsigned char* Ebuf=(unsigned char*)alloc((size_t)66*ITC*16384);

  const float* Zc=Zin;
  for(int l=0;l<4;l++){
    float* Zn = (l==3)? out : ((l&1)? Z1:Z0);
    k_small<<<dim3(33,17),dim3(512),0,stream>>>(Zc,Pm,Qm,YT,PZ);
    k_tr<<<dim3(132),dim3(256),0,stream>>>(Zc,ZT,N1);
    k_scan<<<dim3(4,D),dim3(128),0,stream>>>(PZ,Wf);
    for(int ch=0; ch<c; ch++){
      int tile0 = ch*ITC;
      int nwg = 33*ITC;
      k_qke<<<dim3(nwg),dim3(512),0,stream>>>(ZT,YT,Ebuf,Sp,tile0,ITC,nwg);
      k_ssum<<<dim3((ITC*128+255)/256),dim3(256),0,stream>>>(Sp,S,tile0*128,ITC*128);
      k_v<<<dim3((ITC*4608+255)/256),dim3(256),0,stream>>>(Wf,S,Vt,tile0);
      k_pv<<<dim3(65,ksPC),dim3(512),0,stream>>>(Ebuf,Vt,part,ITC,tile0,ch*ksPC,nT);
    }
    k_out<<<dim3(1033),dim3(256),0,stream>>>(Zc,part,Zn,st);
    Zc=Zn;
  }
}